// Round 10
// baseline (119.261 us; speedup 1.0000x reference)
//
#include <hip/hip_runtime.h>
#include <hip/hip_fp16.h>
#include <math.h>

#define N_FZ    60
#define N_KEZ   20
#define N_TINT  30
#define N_ALPHA 200
#define NORB    2000
#define NTIMES  1000
#define BLOCK   1024
#define ROW_U32 36        // u32 per slab row: 144 B = 9 x 16 B (odd block stride)
#define N_ROWS  199       // a0 ranges 0..198

// ---------------------------------------------------------------------------
// Pass 1: fused transpose + index precompute.
// xd[t][orb] = (xc, dm): xc = clamp(a_ind,0,198.9999) (a0=trunc, dal=fract);
// dm = +inf when geom-masked.
// ---------------------------------------------------------------------------
__global__ __launch_bounds__(256) void prep_kernel(
    const float* __restrict__ alpha,      // (NORB, NTIMES)
    const float* __restrict__ dMag,       // (NORB, NTIMES)
    const float* __restrict__ alphas,     // (N_ALPHA,)
    const float* __restrict__ log_alphas, // (N_ALPHA,)
    float2* __restrict__ xd)              // (NTIMES, NORB)
{
    __shared__ float2 tile[32][33];

    const float la0    = log_alphas[0];
    const float inv_la = 1.0f / (log_alphas[1] - la0);
    const float alo    = alphas[0];
    const float ahi    = alphas[N_ALPHA - 1];

    const int t0 = blockIdx.x * 32;
    const int o0 = blockIdx.y * 32;
    const int tx = threadIdx.x, ty = threadIdx.y;

    #pragma unroll
    for (int r = 0; r < 4; ++r) {
        int orb = o0 + ty + 8 * r;
        int t   = t0 + tx;
        float2 v = make_float2(0.0f, __builtin_inff());
        if (orb < NORB && t < NTIMES) {
            float a  = alpha[(size_t)orb * NTIMES + t];
            float dm = dMag [(size_t)orb * NTIMES + t];
            bool geom = (a >= alo) && (a <= ahi);
            float x = (log10f(a) - la0) * inv_la;
            float xc = fminf(fmaxf(x, 0.0f), 198.9999f);
            v = make_float2(xc, geom ? dm : __builtin_inff());
        }
        tile[ty + 8 * r][tx] = v;
    }
    __syncthreads();
    #pragma unroll
    for (int r = 0; r < 4; ++r) {
        int tt  = ty + 8 * r;
        int t   = t0 + tt;
        int orb = o0 + tx;
        if (orb < NORB && t < NTIMES)
            xd[(size_t)t * NORB + orb] = tile[tx][tt];
    }
}

// ---------------------------------------------------------------------------
// Pass 2: block = one t, 1024 threads (16 waves, 2 blocks/CU = 32 waves/CU).
// Slab in LDS as f16-packed (g0, slope) half2 per (a, tint): one u32/tint,
// row stride 36 u32 (144 B, odd 16B-block stride).  One ds_read_b128 = 4
// tints of one orbit (2x the f32 layout).  dal/dMag stay f32; only the
// interpolated grid value is f16-quantized (err ~0.01 << 1e-2 threshold
// effect on a 1/2000-quantized mean).
// Lane = s*8+h: s = orbit slot (8), h = tint-quad (8; quads 7 has 2 pads,
// pads are 0 -> dim=0 -> never counted since dm >= 20 or +inf).
// Stream: record-pair p = 128j + 8w + s, j=0..6 guard-free + tail (w<13).
// ---------------------------------------------------------------------------
__global__ __launch_bounds__(BLOCK) void pdet8_kernel(
    const float2* __restrict__ xd,        // (NTIMES, NORB)
    const float* __restrict__ fZ_vals,    // (NTIMES,)
    const float* __restrict__ kEZ_val,    // scalar
    const float* __restrict__ grid,       // (N_FZ, N_KEZ, N_TINT, N_ALPHA)
    const float* __restrict__ kEZs,       // (N_KEZ,)
    const float* __restrict__ log_fZs,    // (N_FZ,)
    float* __restrict__ out)              // (NTIMES, N_TINT)
{
    __shared__ __align__(16) unsigned gsT[N_ROWS * ROW_U32];  // 28656 B
    __shared__ int wsum[16][32];                              // 2048 B

    const int t   = blockIdx.x;
    const int tid = threadIdx.x;

    // fZ0 (double to match np at floor boundaries)
    const float lf0    = log_fZs[0];
    const float lfstep = log_fZs[1] - lf0;
    double fZ_ind = (log10((double)fZ_vals[t]) - (double)lf0) * (1.0 / (double)lfstep);
    int fZ0 = (int)floor(fZ_ind) + 1;
    fZ0 = min(max(fZ0, 0), N_FZ - 2);

    // searchsorted(kEZs, kEZ_val, 'right') - 1
    const float kv = kEZ_val[0];
    int kidx = -1;
    #pragma unroll
    for (int i = 0; i < N_KEZ; ++i) kidx += (kEZs[i] <= kv) ? 1 : 0;
    if (kidx < 0) kidx += N_KEZ;

    // ---- stage packed slab: gsT[a][k] = half2(g[k][a], g[k][a+1]-g[k][a]) ----
    // tasks m = k*256 + a; k = 0..31 (30,31 -> zero pads), a = 0..198.
    const float* src = grid + ((size_t)fZ0 * N_KEZ + kidx) * (N_TINT * N_ALPHA);
    for (int m = tid; m < 32 * 256; m += BLOCK) {
        int k = m >> 8;
        int a = m & 255;
        if (a < N_ROWS) {
            unsigned val = 0u;
            if (k < N_TINT) {
                const float* p = src + (size_t)k * N_ALPHA + a;
                float g0 = p[0];
                float g1 = p[1];
                __half2 h2 = __halves2half2(__float2half(g0), __float2half(g1 - g0));
                val = *reinterpret_cast<unsigned*>(&h2);
            }
            gsT[a * ROW_U32 + k] = val;
        }
    }
    __syncthreads();

    const int lane = tid & 63;
    const int w    = tid >> 6;                  // wave 0..15
    const int s    = lane >> 3;                 // orbit slot 0..7
    const int h    = lane & 7;                  // tint quad 0..7
    const int hoff = 4 * h;                     // u32 offset within row

    int c0 = 0, c1 = 0, c2 = 0, c3 = 0;

    // lane's record pair p = 128j + 8w + s at float4 index p
    const float4* rp = reinterpret_cast<const float4*>(xd + (size_t)t * NORB)
                     + 8 * w + s;

    #define EVALREC(XC, DM)                                                      \
    do {                                                                         \
        unsigned a0_ = (unsigned)(XC);                                           \
        float dal_ = __builtin_amdgcn_fractf(XC);                                \
        uint4 U_ = *reinterpret_cast<const uint4*>(&gsT[a0_ * ROW_U32 + hoff]);  \
        __half2 p0_ = *reinterpret_cast<const __half2*>(&U_.x);                  \
        __half2 p1_ = *reinterpret_cast<const __half2*>(&U_.y);                  \
        __half2 p2_ = *reinterpret_cast<const __half2*>(&U_.z);                  \
        __half2 p3_ = *reinterpret_cast<const __half2*>(&U_.w);                  \
        c0 += ((DM) < fmaf(dal_, __half2float(__high2half(p0_)),                 \
                           __half2float(__low2half(p0_)))) ? 1 : 0;              \
        c1 += ((DM) < fmaf(dal_, __half2float(__high2half(p1_)),                 \
                           __half2float(__low2half(p1_)))) ? 1 : 0;              \
        c2 += ((DM) < fmaf(dal_, __half2float(__high2half(p2_)),                 \
                           __half2float(__low2half(p2_)))) ? 1 : 0;              \
        c3 += ((DM) < fmaf(dal_, __half2float(__high2half(p3_)),                 \
                           __half2float(__low2half(p3_)))) ? 1 : 0;              \
    } while (0)

    #pragma unroll 3
    for (int j = 0; j < 7; ++j) {               // p = 128j+8w+s <= 895 < 1000
        float4 v = rp[128 * j];                 // 2 records (8 lanes share addr)
        EVALREC(v.x, v.y);
        EVALREC(v.z, v.w);
    }
    if (w < 13) {                               // tail j=7: p = 896+8w+s <= 999
        float4 v = rp[128 * 7];
        EVALREC(v.x, v.y);
        EVALREC(v.z, v.w);
    }
    #undef EVALREC

    // sum over the 8 orbit slots (lanes sharing h differ in bits 3..5)
    c0 += __shfl_xor(c0, 8, 64);  c0 += __shfl_xor(c0, 16, 64);  c0 += __shfl_xor(c0, 32, 64);
    c1 += __shfl_xor(c1, 8, 64);  c1 += __shfl_xor(c1, 16, 64);  c1 += __shfl_xor(c1, 32, 64);
    c2 += __shfl_xor(c2, 8, 64);  c2 += __shfl_xor(c2, 16, 64);  c2 += __shfl_xor(c2, 32, 64);
    c3 += __shfl_xor(c3, 8, 64);  c3 += __shfl_xor(c3, 16, 64);  c3 += __shfl_xor(c3, 32, 64);
    if (lane < 8) {                             // s==0, h=lane
        wsum[w][4 * lane + 0] = c0;
        wsum[w][4 * lane + 1] = c1;
        wsum[w][4 * lane + 2] = c2;
        wsum[w][4 * lane + 3] = c3;
    }
    __syncthreads();

    if (tid < N_TINT) {
        int tot = 0;
        #pragma unroll
        for (int w2 = 0; w2 < 16; ++w2) tot += wsum[w2][tid];
        out[(size_t)t * N_TINT + tid] = (float)tot * (1.0f / NORB);
    }
}

// ---------------------------------------------------------------------------
// Fallback (no workspace): correct but slower.
// ---------------------------------------------------------------------------
__global__ __launch_bounds__(256) void pdet_kernel(
    const float* __restrict__ alpha, const float* __restrict__ dMag,
    const float* __restrict__ fZ_vals, const float* __restrict__ kEZ_val,
    const float* __restrict__ grid, const float* __restrict__ kEZs,
    const float* __restrict__ alphas, const float* __restrict__ log_fZs,
    const float* __restrict__ log_alphas, float* __restrict__ out)
{
    __shared__ float2 pairs[N_TINT * (N_ALPHA + 1)];
    __shared__ int    wsum[4][N_TINT];

    const int t   = blockIdx.x;
    const int tid = threadIdx.x;

    const float la0    = log_alphas[0];
    const float inv_la = 1.0f / (log_alphas[1] - la0);
    const float alo    = alphas[0];
    const float ahi    = alphas[N_ALPHA - 1];

    const float lf0    = log_fZs[0];
    const float lfstep = log_fZs[1] - lf0;
    double fZ_ind = (log10((double)fZ_vals[t]) - (double)lf0) * (1.0 / (double)lfstep);
    int fZ0 = (int)floor(fZ_ind) + 1;
    fZ0 = min(max(fZ0, 0), N_FZ - 2);

    const float kv = kEZ_val[0];
    int kidx = -1;
    #pragma unroll
    for (int i = 0; i < N_KEZ; ++i) kidx += (kEZs[i] <= kv) ? 1 : 0;
    if (kidx < 0) kidx += N_KEZ;

    const float* src = grid + ((size_t)fZ0 * N_KEZ + kidx) * (N_TINT * N_ALPHA);
    for (int j = tid; j < N_TINT * N_ALPHA; j += 256) {
        int k = j / N_ALPHA;
        int a = j - k * N_ALPHA;
        float g0 = src[j];
        float g1 = (a < N_ALPHA - 1) ? src[j + 1] : g0;
        pairs[k * (N_ALPHA + 1) + a] = make_float2(g0, g1);
    }
    __syncthreads();

    int cnt[N_TINT];
    #pragma unroll
    for (int k = 0; k < N_TINT; ++k) cnt[k] = 0;

    for (int orb = tid; orb < NORB; orb += 256) {
        float a  = alpha[(size_t)orb * NTIMES + t];
        float dm = dMag [(size_t)orb * NTIMES + t];
        bool geom = (a >= alo) && (a <= ahi);
        float a_ind = (log10f(a) - la0) * inv_la;
        int a0 = (int)a_ind;
        a0 = min(max(a0, 0), N_ALPHA - 1);
        float dal = a_ind - (float)a0;
        int a0s = min(a0, N_ALPHA - 2);
        if (!geom) dm = __builtin_inff();

        #pragma unroll
        for (int k = 0; k < N_TINT; ++k) {
            float2 p = pairs[k * (N_ALPHA + 1) + a0s];
            float dim = p.x + dal * (p.y - p.x);
            cnt[k] += (dm < dim) ? 1 : 0;
        }
    }

    const int lane = tid & 63;
    const int wid  = tid >> 6;
    #pragma unroll
    for (int k = 0; k < N_TINT; ++k) {
        int c = cnt[k];
        c += __shfl_xor(c, 32, 64);
        c += __shfl_xor(c, 16, 64);
        c += __shfl_xor(c,  8, 64);
        c += __shfl_xor(c,  4, 64);
        c += __shfl_xor(c,  2, 64);
        c += __shfl_xor(c,  1, 64);
        if (lane == 0) wsum[wid][k] = c;
    }
    __syncthreads();

    if (tid < N_TINT) {
        int tot = wsum[0][tid] + wsum[1][tid] + wsum[2][tid] + wsum[3][tid];
        out[(size_t)t * N_TINT + tid] = (float)tot / (float)NORB;
    }
}

extern "C" void kernel_launch(void* const* d_in, const int* in_sizes, int n_in,
                              void* d_out, int out_size, void* d_ws, size_t ws_size,
                              hipStream_t stream) {
    const float* alpha      = (const float*)d_in[0];
    const float* dMag       = (const float*)d_in[1];
    const float* fZ_vals    = (const float*)d_in[2];
    const float* kEZ_val    = (const float*)d_in[3];
    const float* grid       = (const float*)d_in[4];
    const float* kEZs       = (const float*)d_in[5];
    const float* alphas     = (const float*)d_in[6];
    const float* log_fZs    = (const float*)d_in[7];
    const float* log_alphas = (const float*)d_in[8];
    float* out = (float*)d_out;

    const size_t need = (size_t)NTIMES * NORB * sizeof(float2);
    if (ws_size >= need) {
        dim3 gb((NTIMES + 31) / 32, (NORB + 31) / 32);
        dim3 tb(32, 8);
        prep_kernel<<<gb, tb, 0, stream>>>(alpha, dMag, alphas, log_alphas,
                                           (float2*)d_ws);
        pdet8_kernel<<<NTIMES, BLOCK, 0, stream>>>(
            (const float2*)d_ws, fZ_vals, kEZ_val, grid, kEZs, log_fZs, out);
    } else {
        pdet_kernel<<<NTIMES, 256, 0, stream>>>(
            alpha, dMag, fZ_vals, kEZ_val, grid, kEZs, alphas, log_fZs,
            log_alphas, out);
    }
}